// Round 15
// baseline (93.281 us; speedup 1.0000x reference)
//
#include <hip/hip_runtime.h>

typedef unsigned int u32;
typedef unsigned short u16;

#define B_   2
#define CIN  256
#define COUT 256
#define PD   34
#define PLANE (PD*PD)        // 1156
#define P3   (PD*PD*PD)      // 39304
#define SPAT 32768           // 32*32*32

// xt2: [b][kg(32)][p(P3)][8]  (granule = 8 cin = 16B)
#define XT_BYTES ((size_t)B_ * 32 * P3 * 8 * 2)
#define WB_OFF_BYTES XT_BYTES

typedef __attribute__((ext_vector_type(8)))  short bf16x8;
typedef __attribute__((ext_vector_type(8)))  u16   u16x8;
typedef __attribute__((ext_vector_type(16))) float f32x16;

__device__ __forceinline__ u16 f2bf(float f) {
  union { float f; u32 u; } v; v.f = f;
  u32 r = v.u + 0x7FFFu + ((v.u >> 16) & 1u);   // RNE
  return (u16)(r >> 16);
}

__device__ __forceinline__ void gload_lds16(const void* g, void* l) {
  __builtin_amdgcn_global_load_lds(
      (const __attribute__((address_space(1))) u32*)g,
      (__attribute__((address_space(3))) u32*)l,
      16, 0, 0);
}

__device__ __forceinline__ int tapOff(u32 d) {
  return (d == 1) ? -PLANE : (d == 2) ? PLANE
       : (d == 3) ? -PD    : (d == 4) ? PD
       : (d == 5) ? -1     : (d == 6) ? 1 : 0;
}

// ---------------- zero only the pad border of xt2 ---------------------------
__global__ void zero_border(u16* __restrict__ xt) {
  u32 idx = blockIdx.x * 256u + threadIdx.x;   // 64 * P3 granules
  if (idx >= 64u * (u32)P3) return;
  u32 bk = idx & 63u;                          // b*32 + kg
  u32 p  = idx >> 6;
  u32 t = p / PLANE, rem = p - t * PLANE, r = rem / PD, c = rem - r * PD;
  if (!((t == 0) | (t == 33) | (r == 0) | (r == 33) | (c == 0) | (c == 33)))
    return;
  *(u16x8*)(xt + ((size_t)bk * P3 + p) * 8) = (u16x8)0;
}

// ---------------- W fp32 -> bf16, wb2[d][kg][o][8] ---------------------------
__global__ void convert_w(const float* __restrict__ W, u16* __restrict__ wb) {
  u32 idx = blockIdx.x * 256u + threadIdx.x;   // 7*32*256 = 57344
  u32 o = idx & 255u, kgd = idx >> 8;          // kgd = d*32 + kg
  u32 kg = kgd & 31u, d = kgd >> 5;
  const float* src = W + (size_t)(d * 256u + o) * CIN + kg * 8u;
  float4 f0 = ((const float4*)src)[0];
  float4 f1 = ((const float4*)src)[1];
  u16x8 v;
  v[0] = f2bf(f0.x); v[1] = f2bf(f0.y); v[2] = f2bf(f0.z); v[3] = f2bf(f0.w);
  v[4] = f2bf(f1.x); v[5] = f2bf(f1.y); v[6] = f2bf(f1.z); v[7] = f2bf(f1.w);
  *(u16x8*)(wb + (size_t)idx * 8) = v;
}

// ------- x (b,i,t,r,c) fp32 -> xt2[b][kg][p][8], COALESCED ------------------
__global__ void transpose_pad(const float* __restrict__ x, u16* __restrict__ xt) {
  u32 wg = blockIdx.x;                 // 1024 = b(2) x t(32) x rq(4) x ih(4)
  u32 ih = wg & 3u, rq = (wg >> 2) & 3u, t = (wg >> 4) & 31u, b = wg >> 9;
  u32 tid = threadIdx.x;
  u32 r = tid >> 5, c = tid & 31u, rr = rq * 8u + r;
  u32 sOff = t * 1024u + rr * 32u + c;
  u32 p = ((t + 1) * PD + (rr + 1)) * PD + 1 + c;
#pragma unroll 1
  for (u32 g = 0; g < 8; ++g) {
    u32 ig = ih * 8u + g;
    u16x8 v;
#pragma unroll
    for (int j = 0; j < 8; ++j)
      v[j] = f2bf(x[(size_t)(b * 256u + ig * 8u + (u32)j) * SPAT + sOff]);
    *(u16x8*)(xt + ((size_t)(b * 32u + ig) * P3 + p) * 8) = v;
  }
}

// ---------------- main: 16-wave 256x256 tile, 32x32x16, dbuf BK=64 ----------
// R14 + WAVE-PARITY PHASE STAGGER: odd waves run ks order {2,3,0,1}, even
// waves {0,1,2,3} -> at any instant ~half the block reads LDS while half
// issues MFMA, so the LDS pipe and matrix pipes run CONCURRENTLY instead of
// block-scale burst alternation (the R11/R14 fingerprint: time = LDS + MFMA
// summed serially).
__global__ __launch_bounds__(1024, 4)
void conv_main(const u16* __restrict__ xt, const u16* __restrict__ wb,
               float* __restrict__ out) {
  // [buf][A=0/B=1][kb(8)][row'(256)][8]  = 128 KiB
  __shared__ __align__(16) u16 lds[2][2][8][256][8];

  u32 bid = blockIdx.x;
  u32 id2 = (bid & 7) * 32u + (bid >> 3);    // XCD swizzle (256 % 8 == 0)
  u32 b  = id2 >> 7;
  u32 t  = (id2 >> 2) & 31;
  u32 r0 = (id2 & 3) * 8u;

  u32 tid = threadIdx.x;
  u32 lane = tid & 63, wave = tid >> 6;      // 16 waves
  u32 wm = wave >> 2, wn = wave & 3;         // 4(m) x 4(n) wave grid
  u32 l31 = lane & 31u, lh = lane >> 5;
  u32 kbw = wave & 7u, Hw = wave >> 3;       // staging role

  const u16* xb = xt + (size_t)b * 32u * P3 * 8u;
  u32 pBase = ((t + 1) * PD + (r0 + 1)) * PD + 1;

  u32 aLane = lane * 8u;                                   // u16 units
  u32 bLane = (2u * lh * (u32)PD + l31) * 8u;

  // wave (kbw,Hw) stages its kb-region half (verified R7/R9 maps)
#define STAGE(KN) do {                                                        \
    u32 kn_ = (u32)(KN), buf_ = kn_ & 1u;                                     \
    u32 d_ = kn_ >> 2, kg_ = (kn_ & 3u) * 8u + kbw;                           \
    const u16* gA_ = wb + ((size_t)(d_ * 32u + kg_) * 256u + Hw * 64u) * 8u   \
                        + aLane;                                              \
    u16* dA_ = &lds[buf_][0][kbw][Hw * 128u][0];                              \
    gload_lds16(gA_,          dA_);                                           \
    gload_lds16(gA_ + 1024u,  dA_ + 512u);                                    \
    const u16* gB_ = xb + ((size_t)kg_ * P3                                   \
                          + (u32)((int)pBase + tapOff(d_))                    \
                          + Hw * (u32)PD) * 8u + bLane;                       \
    u16* dB_ = &lds[buf_][1][kbw][Hw * 128u][0];                              \
    gload_lds16(gB_,                    dB_);                                 \
    gload_lds16(gB_ + (u32)(4 * PD * 8), dB_ + 512u);                        \
  } while (0)

  // frag reads for one ks (K=16): 2 A + 2 B ds_read_b128; kb = ks*2 + lh
  u32 aRow = (wm & 1u) * 128u + (wm >> 1) * 64u + l31;
  u32 bRow = (wn >> 1) * 64u + (wn & 1u) * 32u + l31;

#define RD(AS, BS, KS) do {                                                   \
    u32 kb_ = (u32)(KS) * 2u + lh;                                            \
    AS[0] = *(const bf16x8*)&lds[buf][0][kb_][aRow][0];                       \
    AS[1] = *(const bf16x8*)&lds[buf][0][kb_][aRow + 32][0];                  \
    BS[0] = *(const bf16x8*)&lds[buf][1][kb_][bRow][0];                       \
    BS[1] = *(const bf16x8*)&lds[buf][1][kb_][bRow + 128][0];                 \
  } while (0)

#define MF(A, Bv, C) __builtin_amdgcn_mfma_f32_32x32x16_bf16(A, Bv, C, 0, 0, 0)

#define MM(AS, BS) do {                                                       \
    __builtin_amdgcn_s_setprio(1);                                            \
    _Pragma("unroll")                                                         \
    for (int mt = 0; mt < 2; ++mt)                                            \
      _Pragma("unroll")                                                       \
      for (int nt = 0; nt < 2; ++nt)                                          \
        acc[mt][nt] = MF(AS[mt], BS[nt], acc[mt][nt]);                        \
    __builtin_amdgcn_s_setprio(0);                                            \
  } while (0)

  f32x16 acc[2][2];
#pragma unroll
  for (int i = 0; i < 2; ++i)
#pragma unroll
    for (int j = 0; j < 2; ++j) acc[i][j] = (f32x16)0.0f;

  bf16x8 aX[2], bX[2], aY[2], bY[2];

  STAGE(0);
  __syncthreads();                 // drains vmcnt(0): buf0 ready

  const bool odd = (wave & 1u) != 0u;

#pragma unroll 1
  for (int T = 0; T < 28; ++T) {
    const u32 buf = (u32)T & 1u;
    if (T + 1 < 28) STAGE(T + 1);  // issue-first: a full tile to land
    if (odd) {
      // stagger: start at ks2 while even waves start at ks0
      RD(aX, bX, 2);
      RD(aY, bY, 3);
      MM(aX, bX);                  // ks2
      RD(aX, bX, 0);
      MM(aY, bY);                  // ks3
      RD(aY, bY, 1);
      MM(aX, bX);                  // ks0
      MM(aY, bY);                  // ks1
    } else {
      RD(aX, bX, 0);
      RD(aY, bY, 1);
      MM(aX, bX);                  // ks0
      RD(aX, bX, 2);
      MM(aY, bY);                  // ks1
      RD(aY, bY, 3);
      MM(aX, bX);                  // ks2
      MM(aY, bY);                  // ks3
    }
    if (T + 1 < 28) __syncthreads();
  }

#undef MM
#undef MF
#undef RD
#undef STAGE

  // epilogue: 32x32 C/D: col = lane&31 (spatial), row = (reg&3)+8*(reg>>2)
  //           +4*lh (cout within 32)   (verified R4/R9)
  u32 rbase = lh * 4u;
  float* ob = out + (size_t)(b * COUT + wm * 64u) * SPAT
                  + t * 1024u + r0 * 32u;
#pragma unroll
  for (int mt = 0; mt < 2; ++mt)
#pragma unroll
    for (int nt = 0; nt < 2; ++nt) {
      f32x16 v = acc[mt][nt];
#pragma unroll
      for (int reg = 0; reg < 16; ++reg) {
        u32 row = (u32)(reg & 3) + 8u * (u32)(reg >> 2) + rbase;
        ob[(size_t)(mt * 32u + row) * SPAT + wn * 64u + nt * 32u + l31] = v[reg];
      }
    }
}

extern "C" void kernel_launch(void* const* d_in, const int* in_sizes, int n_in,
                              void* d_out, int out_size, void* d_ws, size_t ws_size,
                              hipStream_t stream) {
  const float* x = (const float*)d_in[0];
  const float* W = (const float*)d_in[1];
  float* out = (float*)d_out;
  u16* xt  = (u16*)d_ws;
  u16* wbf = (u16*)((char*)d_ws + WB_OFF_BYTES);

  u32 zThreads = 64u * (u32)P3;
  hipLaunchKernelGGL(zero_border,   dim3((zThreads + 255) / 256), dim3(256), 0, stream, xt);
  hipLaunchKernelGGL(convert_w,     dim3(224),  dim3(256), 0, stream, W, wbf);
  hipLaunchKernelGGL(transpose_pad, dim3(1024), dim3(256), 0, stream, x, xt);
  hipLaunchKernelGGL(conv_main,     dim3(256),  dim3(1024), 0, stream, xt, wbf, out);
}

// Round 16
// 89.408 us; speedup vs baseline: 1.0433x; 1.0433x over previous
//
#include <hip/hip_runtime.h>

typedef unsigned int u32;
typedef unsigned short u16;

#define B_   2
#define CIN  256
#define COUT 256
#define PD   34
#define PLANE (PD*PD)        // 1156
#define P3   (PD*PD*PD)      // 39304
#define SPAT 32768           // 32*32*32

// xt_i8: [b(2)][kg(16)][p(P3)][16]  (granule = 16 cin = 16B)
#define XT_BYTES ((size_t)B_ * 16 * P3 * 16)       // 20,123,648
#define WB_OFF   XT_BYTES
#define WB_BYTES ((size_t)7 * 16 * 256 * 16)       // 458,752
#define WMAX_OFF (WB_OFF + WB_BYTES)

#define SX_RANGE 5.7f

typedef __attribute__((ext_vector_type(4)))  int i32x4;
typedef __attribute__((ext_vector_type(16))) int i32x16;

__device__ __forceinline__ void gload_lds16(const void* g, void* l) {
  __builtin_amdgcn_global_load_lds(
      (const __attribute__((address_space(1))) u32*)g,
      (__attribute__((address_space(3))) u32*)l,
      16, 0, 0);
}

__device__ __forceinline__ int tapOff(u32 d) {
  return (d == 1) ? -PLANE : (d == 2) ? PLANE
       : (d == 3) ? -PD    : (d == 4) ? PD
       : (d == 5) ? -1     : (d == 6) ? 1 : 0;
}

__device__ __forceinline__ char q8(float v, float s) {
  float q = rintf(v * s);
  q = fmaxf(-127.0f, fminf(127.0f, q));
  return (char)(int)q;
}

// ---------------- absmax of W (1.8 MB) -------------------------------------
__global__ void absmax_w(const float* __restrict__ W, u32* __restrict__ wmax) {
  u32 idx = (blockIdx.x * 256u + threadIdx.x) * 4u;   // 448 blocks covers 458752
  float4 f = *(const float4*)(W + idx);
  float m = fmaxf(fmaxf(fabsf(f.x), fabsf(f.y)), fmaxf(fabsf(f.z), fabsf(f.w)));
#pragma unroll
  for (int o = 32; o > 0; o >>= 1) m = fmaxf(m, __shfl_xor(m, o, 64));
  if ((threadIdx.x & 63u) == 0u) atomicMax(wmax, __float_as_uint(m));
}

// ---------------- W -> i8, wb[d][kg(16)][o][16] -----------------------------
__global__ void quant_w(const float* __restrict__ W, char* __restrict__ wb,
                        const u32* __restrict__ wmax) {
  float sw = 127.0f / __uint_as_float(*wmax);
  u32 idx = blockIdx.x * 256u + threadIdx.x;   // 112 blocks = 28672 granules
  u32 o = idx & 255u, kgd = idx >> 8;
  u32 kg = kgd & 15u, d = kgd >> 4;
  const float* src = W + (size_t)(d * 256u + o) * CIN + kg * 16u;
  union { char c[16]; uint4 u; } v;
#pragma unroll
  for (int j = 0; j < 16; ++j) v.c[j] = q8(src[j], sw);
  *(uint4*)(wb + (size_t)idx * 16) = v.u;
}

// ---------------- zero only the pad border of xt ----------------------------
__global__ void zero_border(char* __restrict__ xt) {
  u32 idx = blockIdx.x * 256u + threadIdx.x;   // 32 * P3 granules
  if (idx >= 32u * (u32)P3) return;
  u32 bk = idx & 31u;                          // b*16 + kg
  u32 p  = idx >> 5;
  u32 t = p / PLANE, rem = p - t * PLANE, r = rem / PD, c = rem - r * PD;
  if (!((t == 0) | (t == 33) | (r == 0) | (r == 33) | (c == 0) | (c == 33)))
    return;
  *(uint4*)(xt + ((size_t)bk * P3 + p) * 16) = make_uint4(0, 0, 0, 0);
}

// ------- x fp32 -> i8 xt[b][kg][p][16], coalesced reads ---------------------
__global__ void transpose_quant(const float* __restrict__ x, char* __restrict__ xt) {
  u32 wg = blockIdx.x;                 // 1024 = b(2) x t(32) x rq(4) x ih(4)
  u32 ih = wg & 3u, rq = (wg >> 2) & 3u, t = (wg >> 4) & 31u, b = wg >> 9;
  u32 tid = threadIdx.x;
  u32 r = tid >> 5, c = tid & 31u, rr = rq * 8u + r;
  u32 sOff = t * 1024u + rr * 32u + c;
  u32 p = ((t + 1) * PD + (rr + 1)) * PD + 1 + c;
  const float sx = 127.0f / SX_RANGE;
#pragma unroll 1
  for (u32 g = 0; g < 4; ++g) {
    u32 ig = ih * 4u + g;
    union { char cc[16]; uint4 u; } v;
#pragma unroll
    for (int j = 0; j < 16; ++j)
      v.cc[j] = q8(x[(size_t)(b * 256u + ig * 16u + (u32)j) * SPAT + sOff], sx);
    *(uint4*)(xt + ((size_t)(b * 16u + ig) * P3 + p) * 16) = v.u;
  }
}

// ---------------- main: 8-wave 256x256 tile, i8 32x32x32 MFMA, dbuf BK=64 ---
// R9-verified structure, i8: 28 K-tiles; per wave per tile 4 gload_lds (1KB
// each), 12 ds_read_b128, 16 MFMA i32_32x32x32_i8 (2 ks of K=32), one
// __syncthreads. Exact i32 accumulation; dequant by (SX_RANGE/127)*(wmax/127)
// in the epilogue. LDS 64 KiB.
__global__ __launch_bounds__(512, 2)
void conv_main(const char* __restrict__ xt, const char* __restrict__ wb,
               const u32* __restrict__ wmax, float* __restrict__ out) {
  // [buf][A=0/B=1][kb(4)][row'(256)][16]  = 64 KiB
  __shared__ __align__(16) char lds[2][2][4][256][16];

  u32 bid = blockIdx.x;
  u32 id2 = (bid & 7) * 32u + (bid >> 3);    // XCD swizzle (256 % 8 == 0)
  u32 b  = id2 >> 7;
  u32 t  = (id2 >> 2) & 31;
  u32 r0 = (id2 & 3) * 8u;

  u32 tid = threadIdx.x;
  u32 lane = tid & 63, wave = tid >> 6;
  u32 wm = wave >> 2, wn = wave & 3;         // 2(m) x 4(n) wave grid
  u32 l31 = lane & 31u, lh = lane >> 5;
  u32 pair = wave & 3u, H2 = wave >> 2;      // staging role: kb=pair, half=H2

  const char* xb = xt + (size_t)b * 16u * P3 * 16u;
  u32 pBase = ((t + 1) * PD + (r0 + 1)) * PD + 1;

  u32 aLane = lane * 16u;                                  // bytes
  u32 bLane = (2u * lh * (u32)PD + l31) * 16u;

  // A rows' H*128 + c*64 + l  <->  cout (2c+H)*64 + l   (R7/R9-verified map)
  // B rows' H*128 + c*64 + l  <->  n = (2c+(l>>5))*64 + H*32 + (l&31)
#define STAGE(KN) do {                                                        \
    u32 kn_ = (u32)(KN), buf_ = kn_ & 1u;                                     \
    u32 d_ = kn_ >> 2, kgb_ = (kn_ & 3u) * 4u + pair;                         \
    const char* gA_ = wb + ((size_t)(d_ * 16u + kgb_) * 256u + H2 * 64u) * 16u\
                         + aLane;                                             \
    char* dA_ = &lds[buf_][0][pair][H2 * 128u][0];                            \
    gload_lds16(gA_,          dA_);                                           \
    gload_lds16(gA_ + 2048u,  dA_ + 1024u);                                   \
    const char* gB_ = xb + ((size_t)kgb_ * P3                                 \
                          + (u32)((int)pBase + tapOff(d_))                    \
                          + H2 * (u32)PD) * 16u + bLane;                      \
    char* dB_ = &lds[buf_][1][pair][H2 * 128u][0];                            \
    gload_lds16(gB_,                      dB_);                               \
    gload_lds16(gB_ + (u32)(4 * PD * 16), dB_ + 1024u);                       \
  } while (0)

  // frag reads for one ks (K=32): 4 A + 2 B ds_read_b128; kb = ks*2 + lh
  // A row' = (mt>>1)*128 + wm*64 + (mt&1)*32 + l31
  // B row' = nt*128 + wn*32 + l31
#define RD(AS, BS, KS) do {                                                   \
    u32 kb_ = (u32)(KS) * 2u + lh;                                            \
    _Pragma("unroll")                                                         \
    for (int mt = 0; mt < 4; ++mt)                                            \
      AS[mt] = *(const i32x4*)&lds[buf][0][kb_]                               \
          [(mt >> 1) * 128 + wm * 64 + (mt & 1) * 32 + l31][0];               \
    _Pragma("unroll")                                                         \
    for (int nt = 0; nt < 2; ++nt)                                            \
      BS[nt] = *(const i32x4*)&lds[buf][1][kb_]                               \
          [nt * 128 + wn * 32 + l31][0];                                      \
  } while (0)

#define MF(A, Bv, C) __builtin_amdgcn_mfma_i32_32x32x32_i8(A, Bv, C, 0, 0, 0)

#define MM(AS, BS) do {                                                       \
    __builtin_amdgcn_s_setprio(1);                                            \
    _Pragma("unroll")                                                         \
    for (int mt = 0; mt < 4; ++mt)                                            \
      _Pragma("unroll")                                                       \
      for (int nt = 0; nt < 2; ++nt)                                          \
        acc[mt][nt] = MF(AS[mt], BS[nt], acc[mt][nt]);                        \
    __builtin_amdgcn_s_setprio(0);                                            \
  } while (0)

  i32x16 acc[4][2];
#pragma unroll
  for (int i = 0; i < 4; ++i)
#pragma unroll
    for (int j = 0; j < 2; ++j) acc[i][j] = (i32x16)0;

  i32x4 aX[4], bX[2], aY[4], bY[2];

  STAGE(0);
  __syncthreads();                 // drains vmcnt(0): buf0 ready

#pragma unroll 1
  for (int T = 0; T < 28; ++T) {
    const u32 buf = (u32)T & 1u;
    if (T + 1 < 28) STAGE(T + 1);  // issue-first: a full tile to land
    RD(aX, bX, 0);
    RD(aY, bY, 1);
    MM(aX, bX);                    // ks0 (ks1 reads drain underneath)
    MM(aY, bY);                    // ks1
    if (T + 1 < 28) __syncthreads();
  }

#undef MM
#undef MF
#undef RD
#undef STAGE

  // epilogue: dequant; 32x32 C/D: col = lane&31 (spatial),
  // row = (reg&3)+8*(reg>>2)+4*lh (cout within 32)   (verified R4/R9)
  float wmv = __uint_as_float(*wmax);
  float inv = (SX_RANGE / 127.0f) * (wmv / 127.0f);
  u32 rbase = lh * 4u;
  float* ob = out + (size_t)(b * COUT + wm * 128u) * SPAT
                  + t * 1024u + r0 * 32u;
#pragma unroll
  for (int mt = 0; mt < 4; ++mt)
#pragma unroll
    for (int nt = 0; nt < 2; ++nt) {
      i32x16 v = acc[mt][nt];
#pragma unroll
      for (int reg = 0; reg < 16; ++reg) {
        u32 row = (u32)(reg & 3) + 8u * (u32)(reg >> 2) + rbase;
        ob[(size_t)(mt * 32u + row) * SPAT + wn * 64u + nt * 32u + l31] =
            (float)v[reg] * inv;
      }
    }
}

extern "C" void kernel_launch(void* const* d_in, const int* in_sizes, int n_in,
                              void* d_out, int out_size, void* d_ws, size_t ws_size,
                              hipStream_t stream) {
  const float* x = (const float*)d_in[0];
  const float* W = (const float*)d_in[1];
  float* out = (float*)d_out;
  char* xt  = (char*)d_ws;
  char* wbq = (char*)d_ws + WB_OFF;
  u32*  wmx = (u32*)((char*)d_ws + WMAX_OFF);

  hipMemsetAsync(wmx, 0, 4, stream);
  hipLaunchKernelGGL(absmax_w,        dim3(448),  dim3(256), 0, stream, W, wmx);
  hipLaunchKernelGGL(quant_w,         dim3(112),  dim3(256), 0, stream, W, wbq, wmx);
  u32 zThreads = 32u * (u32)P3;
  hipLaunchKernelGGL(zero_border,     dim3((zThreads + 255) / 256), dim3(256), 0, stream, xt);
  hipLaunchKernelGGL(transpose_quant, dim3(1024), dim3(256), 0, stream, x, xt);
  hipLaunchKernelGGL(conv_main,       dim3(256),  dim3(512), 0, stream, xt, wbq, wmx, out);
}

// Round 17
// 65.743 us; speedup vs baseline: 1.4189x; 1.3600x over previous
//
#include <hip/hip_runtime.h>

typedef unsigned int u32;
typedef unsigned short u16;

#define B_   2
#define CIN  256
#define COUT 256
#define PD   34
#define PLANE (PD*PD)        // 1156
#define P3   (PD*PD*PD)      // 39304
#define SPAT 32768           // 32*32*32

// xt_i8: [b(2)][kg(16)][p(P3)][16]  (granule = 16 cin = 16B)
#define XT_BYTES ((size_t)B_ * 16 * P3 * 16)       // 20,123,648
#define WB_OFF   XT_BYTES
#define WB_BYTES ((size_t)7 * 16 * 256 * 16)       // 458,752
#define PART_OFF (WB_OFF + WB_BYTES)               // 448 floats
#define WMAX_OFF (PART_OFF + 448 * 4)

#define SX_RANGE 5.7f

typedef __attribute__((ext_vector_type(4)))  int i32x4;
typedef __attribute__((ext_vector_type(16))) int i32x16;

__device__ __forceinline__ void gload_lds16(const void* g, void* l) {
  __builtin_amdgcn_global_load_lds(
      (const __attribute__((address_space(1))) u32*)g,
      (__attribute__((address_space(3))) u32*)l,
      16, 0, 0);
}

__device__ __forceinline__ int tapOff(u32 d) {
  return (d == 1) ? -PLANE : (d == 2) ? PLANE
       : (d == 3) ? -PD    : (d == 4) ? PD
       : (d == 5) ? -1     : (d == 6) ? 1 : 0;
}

__device__ __forceinline__ char q8(float v, float s) {
  float q = rintf(v * s);
  q = fmaxf(-127.0f, fminf(127.0f, q));
  return (char)(int)q;
}

// ---------------- absmax of W -> 448 per-block partials (no atomics) --------
__global__ void absmax_w(const float* __restrict__ W, float* __restrict__ part) {
  __shared__ float smax[4];
  u32 tid = threadIdx.x;
  u32 idx = (blockIdx.x * 256u + tid) * 4u;    // 448 blocks cover 458752
  float4 f = *(const float4*)(W + idx);
  float m = fmaxf(fmaxf(fabsf(f.x), fabsf(f.y)), fmaxf(fabsf(f.z), fabsf(f.w)));
#pragma unroll
  for (int o = 32; o > 0; o >>= 1) m = fmaxf(m, __shfl_xor(m, o, 64));
  if ((tid & 63u) == 0u) smax[tid >> 6] = m;
  __syncthreads();
  if (tid == 0u)
    part[blockIdx.x] = fmaxf(fmaxf(smax[0], smax[1]), fmaxf(smax[2], smax[3]));
}

// ---------------- reduce partials + W -> i8 wb[d][kg(16)][o][16] ------------
__global__ void quant_w(const float* __restrict__ W, char* __restrict__ wb,
                        const float* __restrict__ part, float* __restrict__ wmax) {
  __shared__ float smax[4];
  __shared__ float sAll;
  u32 tid = threadIdx.x;
  float m = part[tid < 448u ? tid : 0u];
  if (tid + 256u < 448u) m = fmaxf(m, part[tid + 256u]);
#pragma unroll
  for (int o = 32; o > 0; o >>= 1) m = fmaxf(m, __shfl_xor(m, o, 64));
  if ((tid & 63u) == 0u) smax[tid >> 6] = m;
  __syncthreads();
  if (tid == 0u) {
    float tot = fmaxf(fmaxf(smax[0], smax[1]), fmaxf(smax[2], smax[3]));
    sAll = tot;
    *wmax = tot;                        // same value from every block: benign
  }
  __syncthreads();
  float sw = 127.0f / sAll;

  u32 idx = blockIdx.x * 256u + tid;    // 112 blocks = 28672 granules
  u32 o = idx & 255u, kgd = idx >> 8;
  u32 kg = kgd & 15u, d = kgd >> 4;
  const float* src = W + (size_t)(d * 256u + o) * CIN + kg * 16u;
  union { char c[16]; uint4 u; } v;
#pragma unroll
  for (int j = 0; j < 16; ++j) v.c[j] = q8(src[j], sw);
  *(uint4*)(wb + (size_t)idx * 16) = v.u;
}

// ---- fused: x fp32 -> i8 xt[b][kg][p][16] (float4 reads) + border zero -----
__global__ void prep_x(const float* __restrict__ x, char* __restrict__ xt) {
  u32 bid = blockIdx.x;
  if (bid < 1024u) {
    // transpose-quant: block = one (b, ig, t) plane; lane reads float4
    u32 ig = bid & 15u, t = (bid >> 4) & 31u, b = bid >> 9;
    u32 tid = threadIdx.x;
    u32 quad = tid & 7u, row = tid >> 3;          // 32 rows x 8 quads
    const float sx = 127.0f / SX_RANGE;
    u32 sBase = t * 1024u + row * 32u + quad * 4u;
    u32 p = ((t + 1) * PD + (row + 1)) * PD + 1 + quad * 4u;
    union { char c[16]; uint4 u; } g0, g1, g2, g3;
#pragma unroll
    for (int j = 0; j < 16; ++j) {
      float4 v = *(const float4*)(x + (size_t)(b * 256u + ig * 16u + (u32)j) * SPAT + sBase);
      g0.c[j] = q8(v.x, sx);
      g1.c[j] = q8(v.y, sx);
      g2.c[j] = q8(v.z, sx);
      g3.c[j] = q8(v.w, sx);
    }
    char* dst = xt + ((size_t)(b * 16u + ig) * P3 + p) * 16;
    *(uint4*)(dst)      = g0.u;
    *(uint4*)(dst + 16) = g1.u;
    *(uint4*)(dst + 32) = g2.u;
    *(uint4*)(dst + 48) = g3.u;
  } else {
    // border zero
    u32 idx = (bid - 1024u) * 256u + threadIdx.x;   // 32 * P3 granules
    if (idx >= 32u * (u32)P3) return;
    u32 bk = idx & 31u;
    u32 p  = idx >> 5;
    u32 t = p / PLANE, rem = p - t * PLANE, r = rem / PD, c = rem - r * PD;
    if (!((t == 0) | (t == 33) | (r == 0) | (r == 33) | (c == 0) | (c == 33)))
      return;
    *(uint4*)(xt + ((size_t)bk * P3 + p) * 16) = make_uint4(0, 0, 0, 0);
  }
}

// ---------------- main: 8-wave 256x256 tile, i8 32x32x32 MFMA, dbuf BK=64 ---
// (unchanged from R16: verified 41.3us, absmax 0.078)
__global__ __launch_bounds__(512, 2)
void conv_main(const char* __restrict__ xt, const char* __restrict__ wb,
               const float* __restrict__ wmax, float* __restrict__ out) {
  // [buf][A=0/B=1][kb(4)][row'(256)][16]  = 64 KiB
  __shared__ __align__(16) char lds[2][2][4][256][16];

  u32 bid = blockIdx.x;
  u32 id2 = (bid & 7) * 32u + (bid >> 3);    // XCD swizzle (256 % 8 == 0)
  u32 b  = id2 >> 7;
  u32 t  = (id2 >> 2) & 31;
  u32 r0 = (id2 & 3) * 8u;

  u32 tid = threadIdx.x;
  u32 lane = tid & 63, wave = tid >> 6;
  u32 wm = wave >> 2, wn = wave & 3;         // 2(m) x 4(n) wave grid
  u32 l31 = lane & 31u, lh = lane >> 5;
  u32 pair = wave & 3u, H2 = wave >> 2;      // staging role: kb=pair, half=H2

  const char* xb = xt + (size_t)b * 16u * P3 * 16u;
  u32 pBase = ((t + 1) * PD + (r0 + 1)) * PD + 1;

  u32 aLane = lane * 16u;                                  // bytes
  u32 bLane = (2u * lh * (u32)PD + l31) * 16u;

  // A rows' H*128 + c*64 + l  <->  cout (2c+H)*64 + l   (R7/R9-verified map)
  // B rows' H*128 + c*64 + l  <->  n = (2c+(l>>5))*64 + H*32 + (l&31)
#define STAGE(KN) do {                                                        \
    u32 kn_ = (u32)(KN), buf_ = kn_ & 1u;                                     \
    u32 d_ = kn_ >> 2, kgb_ = (kn_ & 3u) * 4u + pair;                         \
    const char* gA_ = wb + ((size_t)(d_ * 16u + kgb_) * 256u + H2 * 64u) * 16u\
                         + aLane;                                             \
    char* dA_ = &lds[buf_][0][pair][H2 * 128u][0];                            \
    gload_lds16(gA_,          dA_);                                           \
    gload_lds16(gA_ + 2048u,  dA_ + 1024u);                                   \
    const char* gB_ = xb + ((size_t)kgb_ * P3                                 \
                          + (u32)((int)pBase + tapOff(d_))                    \
                          + H2 * (u32)PD) * 16u + bLane;                      \
    char* dB_ = &lds[buf_][1][pair][H2 * 128u][0];                            \
    gload_lds16(gB_,                      dB_);                               \
    gload_lds16(gB_ + (u32)(4 * PD * 16), dB_ + 1024u);                       \
  } while (0)

  // frag reads for one ks (K=32): 4 A + 2 B ds_read_b128; kb = ks*2 + lh
#define RD(AS, BS, KS) do {                                                   \
    u32 kb_ = (u32)(KS) * 2u + lh;                                            \
    _Pragma("unroll")                                                         \
    for (int mt = 0; mt < 4; ++mt)                                            \
      AS[mt] = *(const i32x4*)&lds[buf][0][kb_]                               \
          [(mt >> 1) * 128 + wm * 64 + (mt & 1) * 32 + l31][0];               \
    _Pragma("unroll")                                                         \
    for (int nt = 0; nt < 2; ++nt)                                            \
      BS[nt] = *(const i32x4*)&lds[buf][1][kb_]                               \
          [nt * 128 + wn * 32 + l31][0];                                      \
  } while (0)

#define MF(A, Bv, C) __builtin_amdgcn_mfma_i32_32x32x32_i8(A, Bv, C, 0, 0, 0)

#define MM(AS, BS) do {                                                       \
    __builtin_amdgcn_s_setprio(1);                                            \
    _Pragma("unroll")                                                         \
    for (int mt = 0; mt < 4; ++mt)                                            \
      _Pragma("unroll")                                                       \
      for (int nt = 0; nt < 2; ++nt)                                          \
        acc[mt][nt] = MF(AS[mt], BS[nt], acc[mt][nt]);                        \
    __builtin_amdgcn_s_setprio(0);                                            \
  } while (0)

  i32x16 acc[4][2];
#pragma unroll
  for (int i = 0; i < 4; ++i)
#pragma unroll
    for (int j = 0; j < 2; ++j) acc[i][j] = (i32x16)0;

  i32x4 aX[4], bX[2], aY[4], bY[2];

  STAGE(0);
  __syncthreads();                 // drains vmcnt(0): buf0 ready

#pragma unroll 1
  for (int T = 0; T < 28; ++T) {
    const u32 buf = (u32)T & 1u;
    if (T + 1 < 28) STAGE(T + 1);  // issue-first: a full tile to land
    RD(aX, bX, 0);
    RD(aY, bY, 1);
    MM(aX, bX);                    // ks0 (ks1 reads drain underneath)
    MM(aY, bY);                    // ks1
    if (T + 1 < 28) __syncthreads();
  }

#undef MM
#undef MF
#undef RD
#undef STAGE

  // epilogue: dequant; 32x32 C/D: col = lane&31 (spatial),
  // row = (reg&3)+8*(reg>>2)+4*lh (cout within 32)   (verified R4/R9)
  float inv = (SX_RANGE / 127.0f) * ((*wmax) / 127.0f);
  u32 rbase = lh * 4u;
  float* ob = out + (size_t)(b * COUT + wm * 128u) * SPAT
                  + t * 1024u + r0 * 32u;
#pragma unroll
  for (int mt = 0; mt < 4; ++mt)
#pragma unroll
    for (int nt = 0; nt < 2; ++nt) {
      i32x16 v = acc[mt][nt];
#pragma unroll
      for (int reg = 0; reg < 16; ++reg) {
        u32 row = (u32)(reg & 3) + 8u * (u32)(reg >> 2) + rbase;
        ob[(size_t)(mt * 32u + row) * SPAT + wn * 64u + nt * 32u + l31] =
            (float)v[reg] * inv;
      }
    }
}

extern "C" void kernel_launch(void* const* d_in, const int* in_sizes, int n_in,
                              void* d_out, int out_size, void* d_ws, size_t ws_size,
                              hipStream_t stream) {
  const float* x = (const float*)d_in[0];
  const float* W = (const float*)d_in[1];
  float* out = (float*)d_out;
  char*  xt  = (char*)d_ws;
  char*  wbq = (char*)d_ws + WB_OFF;
  float* prt = (float*)((char*)d_ws + PART_OFF);
  float* wmx = (float*)((char*)d_ws + WMAX_OFF);

  u32 zBlocks = (32u * (u32)P3 + 255u) / 256u;     // 4912
  hipLaunchKernelGGL(absmax_w, dim3(448),           dim3(256), 0, stream, W, prt);
  hipLaunchKernelGGL(quant_w,  dim3(112),           dim3(256), 0, stream, W, wbq, prt, wmx);
  hipLaunchKernelGGL(prep_x,   dim3(1024 + zBlocks), dim3(256), 0, stream, x, xt);
  hipLaunchKernelGGL(conv_main, dim3(256),          dim3(512), 0, stream, xt, wbq, wmx, out);
}